// Round 10
// baseline (330.556 us; speedup 1.0000x reference)
//
#include <hip/hip_runtime.h>
#include <stdint.h>

#define N_ELEM (128*128*128)   // 2097152
#define NBINS 32
#define CAP 32768              // candidates per rank (expected ~13K)
#define REPS 8                 // replicated f64 accumulator sets
#define PBUF 1024              // per-block LDS candidate staging

// ---------------- ws layout (bytes) ----------------
static constexpr size_t OFF_H12  = 0;                                // uint hist12[2][4096] = 32 KB
static constexpr size_t OFF_B12  = OFF_H12 + 2ull*4096ull*4ull;      // uint bucket12[8]
static constexpr size_t OFF_R12  = OFF_B12 + 8*4;                    // uint resid12[8]
static constexpr size_t OFF_CNT  = OFF_R12 + 8*4;                    // uint cnt[8]
static constexpr size_t OFF_SEL  = OFF_CNT + 8*4;                    // float selval[8]
static constexpr size_t OFF_ACC  = (OFF_SEL + 8*4 + 7) & ~size_t(7); // double acc[REPS][2][66]
static constexpr size_t OFF_CAND = OFF_ACC + (size_t)REPS*2*66*8;    // float cand[8][CAP] = 1 MB
static constexpr int ZERO_WORDS  = (int)(OFF_CAND / 4);              // zero [0, OFF_CAND)

// monotonic float <-> uint key
__device__ __forceinline__ uint32_t f2k(float x){
    uint32_t b = __float_as_uint(x);
    return (b & 0x80000000u) ? ~b : (b | 0x80000000u);
}
__device__ __forceinline__ float k2f(uint32_t k){
    uint32_t b = (k & 0x80000000u) ? (k & 0x7FFFFFFFu) : ~k;
    return __uint_as_float(b);
}
__device__ __forceinline__ float fexp2(float x){
#if __has_builtin(__builtin_amdgcn_exp2f)
    return __builtin_amdgcn_exp2f(x);
#else
    return __expf(x * 0.6931471805599453f);
#endif
}
__device__ __forceinline__ float wred(float v){
    #pragma unroll
    for (int o = 32; o > 0; o >>= 1) v += __shfl_down(v, o);
    return v;
}
// native ds_add_f32 (fire-and-forget, no RMW chain); privatized columns -> no contention
__device__ __forceinline__ void lds_fadd(float* p, float v){
    unsafeAtomicAdd(p, v);
}

// ---- Z: zero the control/accumulator region ----
__global__ void __launch_bounds__(256) k_zero(uint32_t* __restrict__ w){
    const int stride = gridDim.x * blockDim.x;
    for (int i = blockIdx.x * blockDim.x + threadIdx.x; i < ZERO_WORDS; i += stride)
        w[i] = 0u;
}

// ---- P1: LDS-private 12-bit histogram (both arrays via blockIdx.y) ----
__global__ void __launch_bounds__(256) k_p1(const float* __restrict__ a0,
                                            const float* __restrict__ a1,
                                            uint32_t* __restrict__ hist12){
    __shared__ uint32_t lh[4096];
    for (int i = threadIdx.x; i < 4096; i += 256) lh[i] = 0;
    __syncthreads();
    const float4* s4 = (const float4*)(blockIdx.y ? a1 : a0);
    const int stride = gridDim.x * blockDim.x;
    for (int i = blockIdx.x * blockDim.x + threadIdx.x; i < N_ELEM/4; i += stride){
        float4 v = s4[i];
        atomicAdd(&lh[f2k(v.x) >> 20], 1u);
        atomicAdd(&lh[f2k(v.y) >> 20], 1u);
        atomicAdd(&lh[f2k(v.z) >> 20], 1u);
        atomicAdd(&lh[f2k(v.w) >> 20], 1u);
    }
    __syncthreads();
    uint32_t* gh = hist12 + (size_t)blockIdx.y * 4096u;
    for (int i = threadIdx.x; i < 4096; i += 256){
        uint32_t c = lh[i];
        if (c) atomicAdd(&gh[i], c);
    }
}

// ---- S1: scan 4096-bin hist (one block per array), locate rank buckets ----
__global__ void __launch_bounds__(256) k_s1(const uint32_t* __restrict__ hist12,
                                            uint32_t* __restrict__ bucket12,
                                            uint32_t* __restrict__ resid12){
    __shared__ uint32_t part[256];
    const uint32_t R[4] = {20971u, 20972u, 2076179u, 2076180u};
    const int a = blockIdx.x;
    const int t = threadIdx.x;
    const uint4* h4 = (const uint4*)(hist12 + (size_t)a * 4096u);
    uint32_t v[16];
    uint32_t s = 0;
    #pragma unroll
    for (int j = 0; j < 4; ++j){
        uint4 q4 = h4[t*4 + j];
        v[j*4+0] = q4.x; v[j*4+1] = q4.y; v[j*4+2] = q4.z; v[j*4+3] = q4.w;
        s += q4.x + q4.y + q4.z + q4.w;
    }
    part[t] = s;
    __syncthreads();
    for (int d = 1; d < 256; d <<= 1){
        uint32_t add = (t >= d) ? part[t - d] : 0u;
        __syncthreads();
        part[t] += add;
        __syncthreads();
    }
    uint32_t c = part[t] - s;
    #pragma unroll
    for (int j = 0; j < 16; ++j){
        uint32_t cnt = v[j];
        if (cnt){
            for (int ri = 0; ri < 4; ++ri){
                uint32_t r = R[ri];
                if (r >= c && r < c + cnt){
                    bucket12[a*4 + ri] = (uint32_t)(t*16 + j);
                    resid12 [a*4 + ri] = r - c;
                }
            }
        }
        c += cnt;
    }
}

// ---- P2: LDS-staged candidate collection (dedup'd buckets) ----
__global__ void __launch_bounds__(256) k_p2(const float* __restrict__ a0,
                                            const float* __restrict__ a1,
                                            const uint32_t* __restrict__ bucket12,
                                            uint32_t* __restrict__ cnt,
                                            float* __restrict__ cand){
    __shared__ uint32_t lcnt[4];
    __shared__ uint32_t gbase[4];
    __shared__ float lbuf[4][PBUF];
    const int t = threadIdx.x;
    const int base = blockIdx.y * 4;
    const uint32_t b0 = bucket12[base+0], b1 = bucket12[base+1];
    const uint32_t b2 = bucket12[base+2], b3 = bucket12[base+3];
    const bool own1 = (b1 != b0);
    const bool own2 = (b2 != b0) && (b2 != b1);
    const bool own3 = (b3 != b0) && (b3 != b1) && (b3 != b2);
    if (t < 4) lcnt[t] = 0;
    __syncthreads();
    const float4* s4 = (const float4*)(blockIdx.y ? a1 : a0);
    const int stride = gridDim.x * blockDim.x;
    for (int i = blockIdx.x * blockDim.x + t; i < N_ELEM/4; i += stride){
        float4 v = s4[i];
        float vv[4] = {v.x, v.y, v.z, v.w};
        #pragma unroll
        for (int e = 0; e < 4; ++e){
            uint32_t hi = f2k(vv[e]) >> 20;
            if (hi == b0){
                uint32_t x = atomicAdd(&lcnt[0], 1u);
                if (x < PBUF) lbuf[0][x] = vv[e];
                else { uint32_t g = atomicAdd(&cnt[base+0], 1u); if (g < CAP) cand[(size_t)(base+0)*CAP + g] = vv[e]; }
            }
            if (own1 && hi == b1){
                uint32_t x = atomicAdd(&lcnt[1], 1u);
                if (x < PBUF) lbuf[1][x] = vv[e];
                else { uint32_t g = atomicAdd(&cnt[base+1], 1u); if (g < CAP) cand[(size_t)(base+1)*CAP + g] = vv[e]; }
            }
            if (own2 && hi == b2){
                uint32_t x = atomicAdd(&lcnt[2], 1u);
                if (x < PBUF) lbuf[2][x] = vv[e];
                else { uint32_t g = atomicAdd(&cnt[base+2], 1u); if (g < CAP) cand[(size_t)(base+2)*CAP + g] = vv[e]; }
            }
            if (own3 && hi == b3){
                uint32_t x = atomicAdd(&lcnt[3], 1u);
                if (x < PBUF) lbuf[3][x] = vv[e];
                else { uint32_t g = atomicAdd(&cnt[base+3], 1u); if (g < CAP) cand[(size_t)(base+3)*CAP + g] = vv[e]; }
            }
        }
    }
    __syncthreads();
    if (t == 0){
        #pragma unroll
        for (int j = 0; j < 4; ++j){
            uint32_t n = min(lcnt[j], (uint32_t)PBUF);
            gbase[j] = n ? atomicAdd(&cnt[base+j], n) : 0u;
        }
    }
    __syncthreads();
    #pragma unroll
    for (int j = 0; j < 4; ++j){
        uint32_t n = min(lcnt[j], (uint32_t)PBUF);
        for (uint32_t i = t; i < n; i += 256){
            uint32_t g = gbase[j] + i;
            if (g < CAP) cand[(size_t)(base+j)*CAP + g] = lbuf[j][i];
        }
    }
}

// ---- S2: in-LDS two-level select of the exact order statistic per rank ----
__global__ void __launch_bounds__(256) k_s2(const float* __restrict__ cand,
                                            const uint32_t* __restrict__ cnt,
                                            const uint32_t* __restrict__ bucket12,
                                            const uint32_t* __restrict__ resid12,
                                            float* __restrict__ selval){
    __shared__ uint32_t lh[1024];
    __shared__ uint32_t part[256];
    __shared__ uint32_t sb_sh, r2_sh;
    const int r = blockIdx.x;
    const int t = threadIdx.x;
    const int base4 = (r >> 2) << 2;
    int o = base4;
    for (int i = base4; i <= r; ++i){
        if (bucket12[i] == bucket12[r]){ o = i; break; }
    }
    const uint32_t n = min(cnt[o], (uint32_t)CAP);
    const float* cb = cand + (size_t)o * CAP;
    const uint32_t rr = resid12[r];
    const uint32_t b12 = bucket12[r];

    for (int i = t; i < 1024; i += 256) lh[i] = 0;
    __syncthreads();
    for (uint32_t i = t; i < n; i += 256) atomicAdd(&lh[(f2k(cb[i]) >> 10) & 1023u], 1u);
    __syncthreads();
    {
        uint32_t v[4]; uint32_t s = 0;
        #pragma unroll
        for (int j = 0; j < 4; ++j){ v[j] = lh[t*4 + j]; s += v[j]; }
        part[t] = s;
        __syncthreads();
        for (int d = 1; d < 256; d <<= 1){
            uint32_t add = (t >= d) ? part[t - d] : 0u;
            __syncthreads();
            part[t] += add;
            __syncthreads();
        }
        uint32_t c = part[t] - s;
        #pragma unroll
        for (int j = 0; j < 4; ++j){
            if (v[j] && rr >= c && rr < c + v[j]){ sb_sh = (uint32_t)(t*4 + j); r2_sh = rr - c; }
            c += v[j];
        }
    }
    __syncthreads();
    const uint32_t sb = sb_sh, r2 = r2_sh;
    __syncthreads();

    for (int i = t; i < 1024; i += 256) lh[i] = 0;
    __syncthreads();
    for (uint32_t i = t; i < n; i += 256){
        uint32_t k = f2k(cb[i]);
        if (((k >> 10) & 1023u) == sb) atomicAdd(&lh[k & 1023u], 1u);
    }
    __syncthreads();
    {
        uint32_t v[4]; uint32_t s = 0;
        #pragma unroll
        for (int j = 0; j < 4; ++j){ v[j] = lh[t*4 + j]; s += v[j]; }
        part[t] = s;
        __syncthreads();
        for (int d = 1; d < 256; d <<= 1){
            uint32_t add = (t >= d) ? part[t - d] : 0u;
            __syncthreads();
            part[t] += add;
            __syncthreads();
        }
        uint32_t c = part[t] - s;
        #pragma unroll
        for (int j = 0; j < 4; ++j){
            if (v[j] && r2 >= c && r2 < c + v[j]){
                uint32_t key = (b12 << 20) | (sb << 10) | (uint32_t)(t*4 + j);
                selval[r] = k2f(key);
            }
            c += v[j];
        }
    }
}

// ---- MAIN: truncated Parzen window, ds_add_f32 into privatized LDS columns ----
__global__ void __launch_bounds__(128) k_main(const float* __restrict__ yt,
                                              const float* __restrict__ yp,
                                              const float* __restrict__ selval,
                                              double* __restrict__ acc){
    __shared__ float lp1[NBINS][128];   // bank = t%32 -> 2-way (free), 0 conflicts (R4 measured)
    __shared__ float lp2[NBINS][128];
    __shared__ float qs[4];
    const int t = threadIdx.x;
    const int dir = blockIdx.y;
    #pragma unroll
    for (int k = 0; k < NBINS; ++k){ lp1[k][t] = 0.f; lp2[k][t] = 0.f; }
    if (t == 0){
        double f01 = 0.01 * (double)(N_ELEM - 1) - 20971.0;     // 0.51
        double f99 = 0.99 * (double)(N_ELEM - 1) - 2076179.0;   // 0.49
        double v0 = selval[0], v1 = selval[1], v2 = selval[2], v3 = selval[3];
        double v4 = selval[4], v5 = selval[5], v6 = selval[6], v7 = selval[7];
        qs[0] = (float)(v0 + f01 * (v1 - v0));   // q01(y_true)
        qs[1] = (float)(v2 + f99 * (v3 - v2));   // q99(y_true)
        qs[2] = (float)(v4 + f01 * (v5 - v4));   // q01(y_pred)
        qs[3] = (float)(v6 + f99 * (v7 - v6));   // q99(y_pred)
    }
    __syncthreads();

    const float f_min = dir ? qs[0] : qs[2];
    const float f_max = dir ? qs[1] : qs[3];
    const float m_min = dir ? qs[2] : qs[0];
    const float m_max = dir ? qs[3] : qs[1];

    const float h      = (f_max - f_min) / 32.0f;
    const float vbc0   = f_min + 0.5f * h;
    const float vbcE   = f_max - 0.5f * h;
    const float step   = (vbcE - vbc0) / 31.0f;
    const float sigma  = step * (1.0f / 2.355f);
    const float preterm= 1.0f / (2.0f * sigma * sigma);
    const float negq2  = -preterm * step * step * 1.4426950408889634f;  // exp2 scale, u-units
    const float inv_st = 1.0f / step;
    const float u0     = -vbc0 * inv_st;

    const float4* ysrc = (const float4*)(dir ? yt : yp);   // target
    const float4* xsrc = (const float4*)(dir ? yp : yt);   // pred

    float sx = 0.f, sxx = 0.f;
    const int stride = gridDim.x * 128;
    for (int i = blockIdx.x * 128 + t; i < N_ELEM/4; i += stride){
        float4 y4 = ysrc[i];
        float4 x4 = xsrc[i];
        float yy[4] = {y4.x, y4.y, y4.z, y4.w};
        float xx[4] = {x4.x, x4.y, x4.z, x4.w};
        #pragma unroll
        for (int e = 0; e < 4; ++e){
            float yc = fminf(fmaxf(yy[e], f_min), f_max);
            float xc = fminf(fmaxf(xx[e], m_min), m_max);
            sx += xc; sxx = fmaf(xc, xc, sxx);
            float u  = fmaf(yc, inv_st, u0);                 // in [-0.5, 31.5]
            float jf = fminf(fmaxf(floorf(u) - 2.0f, 0.0f), 26.0f);
            int j0 = (int)jf;
            float t0 = u - jf;                               // window |u-k| <= 3; miss <= e^-25
            float* p1 = &lp1[j0][t];
            float* p2 = &lp2[j0][t];
            #pragma unroll
            for (int w = 0; w < 6; ++w){
                float d  = t0 - (float)w;
                float wt = fexp2(d * d * negq2);
                lds_fadd(p1 + w*128, wt);        // native ds_add_f32: no read, no chain
                lds_fadd(p2 + w*128, wt * xc);
            }
        }
    }
    __syncthreads();

    // conflict-free column tree: 128 -> 32
    if (t < 64){
        #pragma unroll
        for (int k = 0; k < NBINS; ++k){ lp1[k][t] += lp1[k][t+64]; lp2[k][t] += lp2[k][t+64]; }
    }
    __syncthreads();
    if (t < 32){
        #pragma unroll
        for (int k = 0; k < NBINS; ++k){ lp1[k][t] += lp1[k][t+32]; lp2[k][t] += lp2[k][t+32]; }
    }
    __syncthreads();

    const int rep = blockIdx.x & (REPS - 1);
    double* a = acc + ((size_t)rep*2 + dir) * 66;
    if (t < 64){
        int arr = t >> 5, bin = t & 31;
        float s = 0.f;
        #pragma unroll
        for (int c = 0; c < 32; ++c){
            int cc = (c + t) & 31;   // staggered -> 2-way banks
            s += arr ? lp2[bin][cc] : lp1[bin][cc];
        }
        atomicAdd(&a[t], (double)s);
    }
    sx = wred(sx); sxx = wred(sxx);
    if ((t & 63) == 0){
        atomicAdd(&a[64], (double)sx);
        atomicAdd(&a[65], (double)sxx);
    }
}

// ---- FINAL: reduce replicas + scalar epilogue ----
__global__ void __launch_bounds__(256) k_final(const double* __restrict__ acc,
                                               float* __restrict__ out){
    __shared__ double dA[132];
    const int t = threadIdx.x;
    if (t < 132){
        int dir = t / 66, k = t % 66;
        double s = 0.0;
        #pragma unroll
        for (int rep = 0; rep < REPS; ++rep) s += acc[((size_t)rep*2 + dir)*66 + k];
        dA[t] = s;
    }
    __syncthreads();
    if (t == 0){
        const double eps = 1.1920928955078125e-07;  // finfo(float32).eps
        double res = 0.0;
        for (int dir = 0; dir < 2; ++dir){
            const double* A = &dA[dir*66];
            double sx = A[64], sxx = A[65];
            double tm = sx / (double)N_ELEM;
            double sumS1 = 0.0, bgv = 0.0;
            for (int k = 0; k < NBINS; ++k) sumS1 += A[k];
            for (int k = 0; k < NBINS; ++k){
                double mi = A[32+k] / (A[k] + eps);
                double d  = mi - tm;
                bgv += A[k] * d * d;
            }
            bgv /= (sumS1 + eps);
            double tv = (sxx - sx*sx/(double)N_ELEM) / (double)(N_ELEM - 1);
            res += bgv / (tv + eps);
        }
        out[0] = (float)(-0.5 * res);
    }
}

extern "C" void kernel_launch(void* const* d_in, const int* in_sizes, int n_in,
                              void* d_out, int out_size, void* d_ws, size_t ws_size,
                              hipStream_t stream){
    const float* yt = (const float*)d_in[0];
    const float* yp = (const float*)d_in[1];
    char* ws = (char*)d_ws;
    uint32_t* hist12   = (uint32_t*)(ws + OFF_H12);
    uint32_t* bucket12 = (uint32_t*)(ws + OFF_B12);
    uint32_t* resid12  = (uint32_t*)(ws + OFF_R12);
    uint32_t* cnt      = (uint32_t*)(ws + OFF_CNT);
    float*    selval   = (float*)(ws + OFF_SEL);
    double*   acc      = (double*)(ws + OFF_ACC);
    float*    cand     = (float*)(ws + OFF_CAND);

    k_zero<<<16, 256, 0, stream>>>((uint32_t*)ws);
    k_p1  <<<dim3(256, 2), 256, 0, stream>>>(yt, yp, hist12);
    k_s1  <<<2, 256, 0, stream>>>(hist12, bucket12, resid12);
    k_p2  <<<dim3(128, 2), 256, 0, stream>>>(yt, yp, bucket12, cnt, cand);
    k_s2  <<<8, 256, 0, stream>>>(cand, cnt, bucket12, resid12, selval);
    k_main<<<dim3(512, 2), 128, 0, stream>>>(yt, yp, selval, acc);
    k_final<<<1, 256, 0, stream>>>(acc, (float*)d_out);
}

// Round 11
// 88.700 us; speedup vs baseline: 3.7267x; 3.7267x over previous
//
#include <hip/hip_runtime.h>
#include <stdint.h>

#define N_ELEM (128*128*128)   // 2097152
#define NBINS 32
#define CAP 32768              // candidates per rank (expected ~13K)
#define REPS 8                 // replicated f64 accumulator sets
#define PBUF 1024              // per-block LDS candidate staging

// ---------------- ws layout (bytes) ----------------
static constexpr size_t OFF_H12  = 0;                                // uint hist12[2][4096] = 32 KB
static constexpr size_t OFF_B12  = OFF_H12 + 2ull*4096ull*4ull;      // uint bucket12[8]
static constexpr size_t OFF_R12  = OFF_B12 + 8*4;                    // uint resid12[8]
static constexpr size_t OFF_CNT  = OFF_R12 + 8*4;                    // uint cnt[8]
static constexpr size_t OFF_SEL  = OFF_CNT + 8*4;                    // float selval[8]
static constexpr size_t OFF_ACC  = (OFF_SEL + 8*4 + 7) & ~size_t(7); // double acc[REPS][2][66]
static constexpr size_t OFF_CAND = OFF_ACC + (size_t)REPS*2*66*8;    // float cand[8][CAP] = 1 MB
static constexpr int ZERO_WORDS  = (int)(OFF_CAND / 4);              // zero [0, OFF_CAND)

// monotonic float <-> uint key
__device__ __forceinline__ uint32_t f2k(float x){
    uint32_t b = __float_as_uint(x);
    return (b & 0x80000000u) ? ~b : (b | 0x80000000u);
}
__device__ __forceinline__ float k2f(uint32_t k){
    uint32_t b = (k & 0x80000000u) ? (k & 0x7FFFFFFFu) : ~k;
    return __uint_as_float(b);
}
__device__ __forceinline__ float fexp2(float x){
#if __has_builtin(__builtin_amdgcn_exp2f)
    return __builtin_amdgcn_exp2f(x);
#else
    return __expf(x * 0.6931471805599453f);
#endif
}
__device__ __forceinline__ float wred(float v){
    #pragma unroll
    for (int o = 32; o > 0; o >>= 1) v += __shfl_down(v, o);
    return v;
}

// ---- Z: zero the control/accumulator region ----
__global__ void __launch_bounds__(256) k_zero(uint32_t* __restrict__ w){
    const int stride = gridDim.x * blockDim.x;
    for (int i = blockIdx.x * blockDim.x + threadIdx.x; i < ZERO_WORDS; i += stride)
        w[i] = 0u;
}

// ---- P1: LDS-private 12-bit histogram (both arrays via blockIdx.y) ----
__global__ void __launch_bounds__(256) k_p1(const float* __restrict__ a0,
                                            const float* __restrict__ a1,
                                            uint32_t* __restrict__ hist12){
    __shared__ uint32_t lh[4096];
    for (int i = threadIdx.x; i < 4096; i += 256) lh[i] = 0;
    __syncthreads();
    const float4* s4 = (const float4*)(blockIdx.y ? a1 : a0);
    const int stride = gridDim.x * blockDim.x;
    for (int i = blockIdx.x * blockDim.x + threadIdx.x; i < N_ELEM/4; i += stride){
        float4 v = s4[i];
        atomicAdd(&lh[f2k(v.x) >> 20], 1u);
        atomicAdd(&lh[f2k(v.y) >> 20], 1u);
        atomicAdd(&lh[f2k(v.z) >> 20], 1u);
        atomicAdd(&lh[f2k(v.w) >> 20], 1u);
    }
    __syncthreads();
    uint32_t* gh = hist12 + (size_t)blockIdx.y * 4096u;
    for (int i = threadIdx.x; i < 4096; i += 256){
        uint32_t c = lh[i];
        if (c) atomicAdd(&gh[i], c);
    }
}

// ---- S1: scan 4096-bin hist (one block per array), locate rank buckets ----
__global__ void __launch_bounds__(256) k_s1(const uint32_t* __restrict__ hist12,
                                            uint32_t* __restrict__ bucket12,
                                            uint32_t* __restrict__ resid12){
    __shared__ uint32_t part[256];
    const uint32_t R[4] = {20971u, 20972u, 2076179u, 2076180u};
    const int a = blockIdx.x;
    const int t = threadIdx.x;
    const uint4* h4 = (const uint4*)(hist12 + (size_t)a * 4096u);
    uint32_t v[16];
    uint32_t s = 0;
    #pragma unroll
    for (int j = 0; j < 4; ++j){
        uint4 q4 = h4[t*4 + j];
        v[j*4+0] = q4.x; v[j*4+1] = q4.y; v[j*4+2] = q4.z; v[j*4+3] = q4.w;
        s += q4.x + q4.y + q4.z + q4.w;
    }
    part[t] = s;
    __syncthreads();
    for (int d = 1; d < 256; d <<= 1){
        uint32_t add = (t >= d) ? part[t - d] : 0u;
        __syncthreads();
        part[t] += add;
        __syncthreads();
    }
    uint32_t c = part[t] - s;
    #pragma unroll
    for (int j = 0; j < 16; ++j){
        uint32_t cnt = v[j];
        if (cnt){
            for (int ri = 0; ri < 4; ++ri){
                uint32_t r = R[ri];
                if (r >= c && r < c + cnt){
                    bucket12[a*4 + ri] = (uint32_t)(t*16 + j);
                    resid12 [a*4 + ri] = r - c;
                }
            }
        }
        c += cnt;
    }
}

// ---- P2: LDS-staged candidate collection (dedup'd buckets) ----
__global__ void __launch_bounds__(256) k_p2(const float* __restrict__ a0,
                                            const float* __restrict__ a1,
                                            const uint32_t* __restrict__ bucket12,
                                            uint32_t* __restrict__ cnt,
                                            float* __restrict__ cand){
    __shared__ uint32_t lcnt[4];
    __shared__ uint32_t gbase[4];
    __shared__ float lbuf[4][PBUF];
    const int t = threadIdx.x;
    const int base = blockIdx.y * 4;
    const uint32_t b0 = bucket12[base+0], b1 = bucket12[base+1];
    const uint32_t b2 = bucket12[base+2], b3 = bucket12[base+3];
    const bool own1 = (b1 != b0);
    const bool own2 = (b2 != b0) && (b2 != b1);
    const bool own3 = (b3 != b0) && (b3 != b1) && (b3 != b2);
    if (t < 4) lcnt[t] = 0;
    __syncthreads();
    const float4* s4 = (const float4*)(blockIdx.y ? a1 : a0);
    const int stride = gridDim.x * blockDim.x;
    for (int i = blockIdx.x * blockDim.x + t; i < N_ELEM/4; i += stride){
        float4 v = s4[i];
        float vv[4] = {v.x, v.y, v.z, v.w};
        #pragma unroll
        for (int e = 0; e < 4; ++e){
            uint32_t hi = f2k(vv[e]) >> 20;
            if (hi == b0){
                uint32_t x = atomicAdd(&lcnt[0], 1u);
                if (x < PBUF) lbuf[0][x] = vv[e];
                else { uint32_t g = atomicAdd(&cnt[base+0], 1u); if (g < CAP) cand[(size_t)(base+0)*CAP + g] = vv[e]; }
            }
            if (own1 && hi == b1){
                uint32_t x = atomicAdd(&lcnt[1], 1u);
                if (x < PBUF) lbuf[1][x] = vv[e];
                else { uint32_t g = atomicAdd(&cnt[base+1], 1u); if (g < CAP) cand[(size_t)(base+1)*CAP + g] = vv[e]; }
            }
            if (own2 && hi == b2){
                uint32_t x = atomicAdd(&lcnt[2], 1u);
                if (x < PBUF) lbuf[2][x] = vv[e];
                else { uint32_t g = atomicAdd(&cnt[base+2], 1u); if (g < CAP) cand[(size_t)(base+2)*CAP + g] = vv[e]; }
            }
            if (own3 && hi == b3){
                uint32_t x = atomicAdd(&lcnt[3], 1u);
                if (x < PBUF) lbuf[3][x] = vv[e];
                else { uint32_t g = atomicAdd(&cnt[base+3], 1u); if (g < CAP) cand[(size_t)(base+3)*CAP + g] = vv[e]; }
            }
        }
    }
    __syncthreads();
    if (t == 0){
        #pragma unroll
        for (int j = 0; j < 4; ++j){
            uint32_t n = min(lcnt[j], (uint32_t)PBUF);
            gbase[j] = n ? atomicAdd(&cnt[base+j], n) : 0u;
        }
    }
    __syncthreads();
    #pragma unroll
    for (int j = 0; j < 4; ++j){
        uint32_t n = min(lcnt[j], (uint32_t)PBUF);
        for (uint32_t i = t; i < n; i += 256){
            uint32_t g = gbase[j] + i;
            if (g < CAP) cand[(size_t)(base+j)*CAP + g] = lbuf[j][i];
        }
    }
}

// ---- S2: in-LDS two-level select of the exact order statistic per rank ----
__global__ void __launch_bounds__(256) k_s2(const float* __restrict__ cand,
                                            const uint32_t* __restrict__ cnt,
                                            const uint32_t* __restrict__ bucket12,
                                            const uint32_t* __restrict__ resid12,
                                            float* __restrict__ selval){
    __shared__ uint32_t lh[1024];
    __shared__ uint32_t part[256];
    __shared__ uint32_t sb_sh, r2_sh;
    const int r = blockIdx.x;
    const int t = threadIdx.x;
    const int base4 = (r >> 2) << 2;
    int o = base4;
    for (int i = base4; i <= r; ++i){
        if (bucket12[i] == bucket12[r]){ o = i; break; }
    }
    const uint32_t n = min(cnt[o], (uint32_t)CAP);
    const float* cb = cand + (size_t)o * CAP;
    const uint32_t rr = resid12[r];
    const uint32_t b12 = bucket12[r];

    for (int i = t; i < 1024; i += 256) lh[i] = 0;
    __syncthreads();
    for (uint32_t i = t; i < n; i += 256) atomicAdd(&lh[(f2k(cb[i]) >> 10) & 1023u], 1u);
    __syncthreads();
    {
        uint32_t v[4]; uint32_t s = 0;
        #pragma unroll
        for (int j = 0; j < 4; ++j){ v[j] = lh[t*4 + j]; s += v[j]; }
        part[t] = s;
        __syncthreads();
        for (int d = 1; d < 256; d <<= 1){
            uint32_t add = (t >= d) ? part[t - d] : 0u;
            __syncthreads();
            part[t] += add;
            __syncthreads();
        }
        uint32_t c = part[t] - s;
        #pragma unroll
        for (int j = 0; j < 4; ++j){
            if (v[j] && rr >= c && rr < c + v[j]){ sb_sh = (uint32_t)(t*4 + j); r2_sh = rr - c; }
            c += v[j];
        }
    }
    __syncthreads();
    const uint32_t sb = sb_sh, r2 = r2_sh;
    __syncthreads();

    for (int i = t; i < 1024; i += 256) lh[i] = 0;
    __syncthreads();
    for (uint32_t i = t; i < n; i += 256){
        uint32_t k = f2k(cb[i]);
        if (((k >> 10) & 1023u) == sb) atomicAdd(&lh[k & 1023u], 1u);
    }
    __syncthreads();
    {
        uint32_t v[4]; uint32_t s = 0;
        #pragma unroll
        for (int j = 0; j < 4; ++j){ v[j] = lh[t*4 + j]; s += v[j]; }
        part[t] = s;
        __syncthreads();
        for (int d = 1; d < 256; d <<= 1){
            uint32_t add = (t >= d) ? part[t - d] : 0u;
            __syncthreads();
            part[t] += add;
            __syncthreads();
        }
        uint32_t c = part[t] - s;
        #pragma unroll
        for (int j = 0; j < 4; ++j){
            if (v[j] && r2 >= c && r2 < c + v[j]){
                uint32_t key = (b12 << 20) | (sb << 10) | (uint32_t)(t*4 + j);
                selval[r] = k2f(key);
            }
            c += v[j];
        }
    }
}

// ---- MAIN: 4-bin truncated Parzen window, per-thread privatized LDS columns ----
__global__ void __launch_bounds__(128) k_main(const float* __restrict__ yt,
                                              const float* __restrict__ yp,
                                              const float* __restrict__ selval,
                                              double* __restrict__ acc){
    __shared__ float lp1[NBINS][128];   // bank = t%32 -> 2-way (free), 0 conflicts (R4 measured)
    __shared__ float lp2[NBINS][128];
    __shared__ float qs[4];
    const int t = threadIdx.x;
    const int dir = blockIdx.y;
    #pragma unroll
    for (int k = 0; k < NBINS; ++k){ lp1[k][t] = 0.f; lp2[k][t] = 0.f; }
    if (t == 0){
        double f01 = 0.01 * (double)(N_ELEM - 1) - 20971.0;     // 0.51
        double f99 = 0.99 * (double)(N_ELEM - 1) - 2076179.0;   // 0.49
        double v0 = selval[0], v1 = selval[1], v2 = selval[2], v3 = selval[3];
        double v4 = selval[4], v5 = selval[5], v6 = selval[6], v7 = selval[7];
        qs[0] = (float)(v0 + f01 * (v1 - v0));   // q01(y_true)
        qs[1] = (float)(v2 + f99 * (v3 - v2));   // q99(y_true)
        qs[2] = (float)(v4 + f01 * (v5 - v4));   // q01(y_pred)
        qs[3] = (float)(v6 + f99 * (v7 - v6));   // q99(y_pred)
    }
    __syncthreads();

    const float f_min = dir ? qs[0] : qs[2];
    const float f_max = dir ? qs[1] : qs[3];
    const float m_min = dir ? qs[2] : qs[0];
    const float m_max = dir ? qs[3] : qs[1];

    const float h      = (f_max - f_min) / 32.0f;
    const float vbc0   = f_min + 0.5f * h;
    const float vbcE   = f_max - 0.5f * h;
    const float step   = (vbcE - vbc0) / 31.0f;
    const float sigma  = step * (1.0f / 2.355f);
    const float preterm= 1.0f / (2.0f * sigma * sigma);
    const float negq2  = -preterm * step * step * 1.4426950408889634f;  // exp2 scale, u-units
    const float inv_st = 1.0f / step;
    const float u0     = -vbc0 * inv_st;

    const float4* ysrc = (const float4*)(dir ? yt : yp);   // target
    const float4* xsrc = (const float4*)(dir ? yp : yt);   // pred

    float sx = 0.f, sxx = 0.f;
    const int stride = gridDim.x * 128;
    for (int i = blockIdx.x * 128 + t; i < N_ELEM/4; i += stride){
        float4 y4 = ysrc[i];
        float4 x4 = xsrc[i];
        float yy[4] = {y4.x, y4.y, y4.z, y4.w};
        float xx[4] = {x4.x, x4.y, x4.z, x4.w};
        #pragma unroll
        for (int e = 0; e < 4; ++e){
            float yc = fminf(fmaxf(yy[e], f_min), f_max);
            float xc = fminf(fmaxf(xx[e], m_min), m_max);
            sx += xc; sxx = fmaf(xc, xc, sxx);
            float u  = fmaf(yc, inv_st, u0);                 // in [-0.5, 31.5]
            float jf = fminf(fmaxf(floorf(u) - 1.0f, 0.0f), 28.0f);
            int j0 = (int)jf;
            float t0 = u - jf;                               // window |u-k| <= 2; miss <= 1.6e-5 rel
            float* p1 = &lp1[j0][t];
            float* p2 = &lp2[j0][t];
            #pragma unroll
            for (int w = 0; w < 4; ++w){
                float d  = t0 - (float)w;
                float wt = fexp2(d * d * negq2);
                p1[w*128] += wt;
                p2[w*128] += wt * xc;
            }
        }
    }
    __syncthreads();

    // conflict-free column tree: 128 -> 32
    if (t < 64){
        #pragma unroll
        for (int k = 0; k < NBINS; ++k){ lp1[k][t] += lp1[k][t+64]; lp2[k][t] += lp2[k][t+64]; }
    }
    __syncthreads();
    if (t < 32){
        #pragma unroll
        for (int k = 0; k < NBINS; ++k){ lp1[k][t] += lp1[k][t+32]; lp2[k][t] += lp2[k][t+32]; }
    }
    __syncthreads();

    const int rep = blockIdx.x & (REPS - 1);
    double* a = acc + ((size_t)rep*2 + dir) * 66;
    if (t < 64){
        int arr = t >> 5, bin = t & 31;
        float s = 0.f;
        #pragma unroll
        for (int c = 0; c < 32; ++c){
            int cc = (c + t) & 31;   // staggered -> 2-way banks
            s += arr ? lp2[bin][cc] : lp1[bin][cc];
        }
        atomicAdd(&a[t], (double)s);
    }
    sx = wred(sx); sxx = wred(sxx);
    if ((t & 63) == 0){
        atomicAdd(&a[64], (double)sx);
        atomicAdd(&a[65], (double)sxx);
    }
}

// ---- FINAL: reduce replicas + scalar epilogue ----
__global__ void __launch_bounds__(256) k_final(const double* __restrict__ acc,
                                               float* __restrict__ out){
    __shared__ double dA[132];
    const int t = threadIdx.x;
    if (t < 132){
        int dir = t / 66, k = t % 66;
        double s = 0.0;
        #pragma unroll
        for (int rep = 0; rep < REPS; ++rep) s += acc[((size_t)rep*2 + dir)*66 + k];
        dA[t] = s;
    }
    __syncthreads();
    if (t == 0){
        const double eps = 1.1920928955078125e-07;  // finfo(float32).eps
        double res = 0.0;
        for (int dir = 0; dir < 2; ++dir){
            const double* A = &dA[dir*66];
            double sx = A[64], sxx = A[65];
            double tm = sx / (double)N_ELEM;
            double sumS1 = 0.0, bgv = 0.0;
            for (int k = 0; k < NBINS; ++k) sumS1 += A[k];
            for (int k = 0; k < NBINS; ++k){
                double mi = A[32+k] / (A[k] + eps);
                double d  = mi - tm;
                bgv += A[k] * d * d;
            }
            bgv /= (sumS1 + eps);
            double tv = (sxx - sx*sx/(double)N_ELEM) / (double)(N_ELEM - 1);
            res += bgv / (tv + eps);
        }
        out[0] = (float)(-0.5 * res);
    }
}

extern "C" void kernel_launch(void* const* d_in, const int* in_sizes, int n_in,
                              void* d_out, int out_size, void* d_ws, size_t ws_size,
                              hipStream_t stream){
    const float* yt = (const float*)d_in[0];
    const float* yp = (const float*)d_in[1];
    char* ws = (char*)d_ws;
    uint32_t* hist12   = (uint32_t*)(ws + OFF_H12);
    uint32_t* bucket12 = (uint32_t*)(ws + OFF_B12);
    uint32_t* resid12  = (uint32_t*)(ws + OFF_R12);
    uint32_t* cnt      = (uint32_t*)(ws + OFF_CNT);
    float*    selval   = (float*)(ws + OFF_SEL);
    double*   acc      = (double*)(ws + OFF_ACC);
    float*    cand     = (float*)(ws + OFF_CAND);

    k_zero<<<16, 256, 0, stream>>>((uint32_t*)ws);
    k_p1  <<<dim3(256, 2), 256, 0, stream>>>(yt, yp, hist12);
    k_s1  <<<2, 256, 0, stream>>>(hist12, bucket12, resid12);
    k_p2  <<<dim3(128, 2), 256, 0, stream>>>(yt, yp, bucket12, cnt, cand);
    k_s2  <<<8, 256, 0, stream>>>(cand, cnt, bucket12, resid12, selval);
    k_main<<<dim3(512, 2), 128, 0, stream>>>(yt, yp, selval, acc);
    k_final<<<1, 256, 0, stream>>>(acc, (float*)d_out);
}

// Round 12
// 87.668 us; speedup vs baseline: 3.7706x; 1.0118x over previous
//
#include <hip/hip_runtime.h>
#include <stdint.h>

#define N_ELEM (128*128*128)   // 2097152
#define NBINS 32
#define CAP 32768              // candidates per rank (expected ~13K)
#define REPS 8                 // replicated f64 accumulator sets
#define PBUF 1024              // per-block LDS candidate staging

// ---------------- ws layout (bytes) ----------------
static constexpr size_t OFF_H12  = 0;                                // uint hist12[2][4096] = 32 KB
static constexpr size_t OFF_B12  = OFF_H12 + 2ull*4096ull*4ull;      // uint bucket12[8]
static constexpr size_t OFF_R12  = OFF_B12 + 8*4;                    // uint resid12[8]
static constexpr size_t OFF_CNT  = OFF_R12 + 8*4;                    // uint cnt[8]
static constexpr size_t OFF_SEL  = OFF_CNT + 8*4;                    // float selval[8]
static constexpr size_t OFF_ACC  = (OFF_SEL + 8*4 + 7) & ~size_t(7); // double acc[REPS][2][66]
static constexpr size_t OFF_CAND = OFF_ACC + (size_t)REPS*2*66*8;    // float cand[8][CAP] = 1 MB
static constexpr int ZERO_WORDS  = (int)(OFF_CAND / 4);              // zero [0, OFF_CAND)

// monotonic float <-> uint key
__device__ __forceinline__ uint32_t f2k(float x){
    uint32_t b = __float_as_uint(x);
    return (b & 0x80000000u) ? ~b : (b | 0x80000000u);
}
__device__ __forceinline__ float k2f(uint32_t k){
    uint32_t b = (k & 0x80000000u) ? (k & 0x7FFFFFFFu) : ~k;
    return __uint_as_float(b);
}
__device__ __forceinline__ float fexp2(float x){
#if __has_builtin(__builtin_amdgcn_exp2f)
    return __builtin_amdgcn_exp2f(x);
#else
    return __expf(x * 0.6931471805599453f);
#endif
}
__device__ __forceinline__ float wred(float v){
    #pragma unroll
    for (int o = 32; o > 0; o >>= 1) v += __shfl_down(v, o);
    return v;
}

// ---- Z: zero the control/accumulator region ----
__global__ void __launch_bounds__(256) k_zero(uint32_t* __restrict__ w){
    const int stride = gridDim.x * blockDim.x;
    for (int i = blockIdx.x * blockDim.x + threadIdx.x; i < ZERO_WORDS; i += stride)
        w[i] = 0u;
}

// ---- P1: LDS-private 12-bit histogram (both arrays via blockIdx.y) ----
__global__ void __launch_bounds__(256) k_p1(const float* __restrict__ a0,
                                            const float* __restrict__ a1,
                                            uint32_t* __restrict__ hist12){
    __shared__ uint32_t lh[4096];
    for (int i = threadIdx.x; i < 4096; i += 256) lh[i] = 0;
    __syncthreads();
    const float4* s4 = (const float4*)(blockIdx.y ? a1 : a0);
    const int stride = gridDim.x * blockDim.x;
    for (int i = blockIdx.x * blockDim.x + threadIdx.x; i < N_ELEM/4; i += stride){
        float4 v = s4[i];
        atomicAdd(&lh[f2k(v.x) >> 20], 1u);
        atomicAdd(&lh[f2k(v.y) >> 20], 1u);
        atomicAdd(&lh[f2k(v.z) >> 20], 1u);
        atomicAdd(&lh[f2k(v.w) >> 20], 1u);
    }
    __syncthreads();
    uint32_t* gh = hist12 + (size_t)blockIdx.y * 4096u;
    for (int i = threadIdx.x; i < 4096; i += 256){
        uint32_t c = lh[i];
        if (c) atomicAdd(&gh[i], c);
    }
}

// ---- S1: scan 4096-bin hist (one block per array), locate rank buckets ----
__global__ void __launch_bounds__(256) k_s1(const uint32_t* __restrict__ hist12,
                                            uint32_t* __restrict__ bucket12,
                                            uint32_t* __restrict__ resid12){
    __shared__ uint32_t part[256];
    const uint32_t R[4] = {20971u, 20972u, 2076179u, 2076180u};
    const int a = blockIdx.x;
    const int t = threadIdx.x;
    const uint4* h4 = (const uint4*)(hist12 + (size_t)a * 4096u);
    uint32_t v[16];
    uint32_t s = 0;
    #pragma unroll
    for (int j = 0; j < 4; ++j){
        uint4 q4 = h4[t*4 + j];
        v[j*4+0] = q4.x; v[j*4+1] = q4.y; v[j*4+2] = q4.z; v[j*4+3] = q4.w;
        s += q4.x + q4.y + q4.z + q4.w;
    }
    part[t] = s;
    __syncthreads();
    for (int d = 1; d < 256; d <<= 1){
        uint32_t add = (t >= d) ? part[t - d] : 0u;
        __syncthreads();
        part[t] += add;
        __syncthreads();
    }
    uint32_t c = part[t] - s;
    #pragma unroll
    for (int j = 0; j < 16; ++j){
        uint32_t cnt = v[j];
        if (cnt){
            for (int ri = 0; ri < 4; ++ri){
                uint32_t r = R[ri];
                if (r >= c && r < c + cnt){
                    bucket12[a*4 + ri] = (uint32_t)(t*16 + j);
                    resid12 [a*4 + ri] = r - c;
                }
            }
        }
        c += cnt;
    }
}

// ---- P2: LDS-staged candidate collection (dedup'd buckets) ----
__global__ void __launch_bounds__(256) k_p2(const float* __restrict__ a0,
                                            const float* __restrict__ a1,
                                            const uint32_t* __restrict__ bucket12,
                                            uint32_t* __restrict__ cnt,
                                            float* __restrict__ cand){
    __shared__ uint32_t lcnt[4];
    __shared__ uint32_t gbase[4];
    __shared__ float lbuf[4][PBUF];
    const int t = threadIdx.x;
    const int base = blockIdx.y * 4;
    const uint32_t b0 = bucket12[base+0], b1 = bucket12[base+1];
    const uint32_t b2 = bucket12[base+2], b3 = bucket12[base+3];
    const bool own1 = (b1 != b0);
    const bool own2 = (b2 != b0) && (b2 != b1);
    const bool own3 = (b3 != b0) && (b3 != b1) && (b3 != b2);
    if (t < 4) lcnt[t] = 0;
    __syncthreads();
    const float4* s4 = (const float4*)(blockIdx.y ? a1 : a0);
    const int stride = gridDim.x * blockDim.x;
    for (int i = blockIdx.x * blockDim.x + t; i < N_ELEM/4; i += stride){
        float4 v = s4[i];
        float vv[4] = {v.x, v.y, v.z, v.w};
        #pragma unroll
        for (int e = 0; e < 4; ++e){
            uint32_t hi = f2k(vv[e]) >> 20;
            if (hi == b0){
                uint32_t x = atomicAdd(&lcnt[0], 1u);
                if (x < PBUF) lbuf[0][x] = vv[e];
                else { uint32_t g = atomicAdd(&cnt[base+0], 1u); if (g < CAP) cand[(size_t)(base+0)*CAP + g] = vv[e]; }
            }
            if (own1 && hi == b1){
                uint32_t x = atomicAdd(&lcnt[1], 1u);
                if (x < PBUF) lbuf[1][x] = vv[e];
                else { uint32_t g = atomicAdd(&cnt[base+1], 1u); if (g < CAP) cand[(size_t)(base+1)*CAP + g] = vv[e]; }
            }
            if (own2 && hi == b2){
                uint32_t x = atomicAdd(&lcnt[2], 1u);
                if (x < PBUF) lbuf[2][x] = vv[e];
                else { uint32_t g = atomicAdd(&cnt[base+2], 1u); if (g < CAP) cand[(size_t)(base+2)*CAP + g] = vv[e]; }
            }
            if (own3 && hi == b3){
                uint32_t x = atomicAdd(&lcnt[3], 1u);
                if (x < PBUF) lbuf[3][x] = vv[e];
                else { uint32_t g = atomicAdd(&cnt[base+3], 1u); if (g < CAP) cand[(size_t)(base+3)*CAP + g] = vv[e]; }
            }
        }
    }
    __syncthreads();
    if (t == 0){
        #pragma unroll
        for (int j = 0; j < 4; ++j){
            uint32_t n = min(lcnt[j], (uint32_t)PBUF);
            gbase[j] = n ? atomicAdd(&cnt[base+j], n) : 0u;
        }
    }
    __syncthreads();
    #pragma unroll
    for (int j = 0; j < 4; ++j){
        uint32_t n = min(lcnt[j], (uint32_t)PBUF);
        for (uint32_t i = t; i < n; i += 256){
            uint32_t g = gbase[j] + i;
            if (g < CAP) cand[(size_t)(base+j)*CAP + g] = lbuf[j][i];
        }
    }
}

// ---- S2: in-LDS two-level select of the exact order statistic per rank ----
__global__ void __launch_bounds__(256) k_s2(const float* __restrict__ cand,
                                            const uint32_t* __restrict__ cnt,
                                            const uint32_t* __restrict__ bucket12,
                                            const uint32_t* __restrict__ resid12,
                                            float* __restrict__ selval){
    __shared__ uint32_t lh[1024];
    __shared__ uint32_t part[256];
    __shared__ uint32_t sb_sh, r2_sh;
    const int r = blockIdx.x;
    const int t = threadIdx.x;
    const int base4 = (r >> 2) << 2;
    int o = base4;
    for (int i = base4; i <= r; ++i){
        if (bucket12[i] == bucket12[r]){ o = i; break; }
    }
    const uint32_t n = min(cnt[o], (uint32_t)CAP);
    const float* cb = cand + (size_t)o * CAP;
    const uint32_t rr = resid12[r];
    const uint32_t b12 = bucket12[r];

    for (int i = t; i < 1024; i += 256) lh[i] = 0;
    __syncthreads();
    for (uint32_t i = t; i < n; i += 256) atomicAdd(&lh[(f2k(cb[i]) >> 10) & 1023u], 1u);
    __syncthreads();
    {
        uint32_t v[4]; uint32_t s = 0;
        #pragma unroll
        for (int j = 0; j < 4; ++j){ v[j] = lh[t*4 + j]; s += v[j]; }
        part[t] = s;
        __syncthreads();
        for (int d = 1; d < 256; d <<= 1){
            uint32_t add = (t >= d) ? part[t - d] : 0u;
            __syncthreads();
            part[t] += add;
            __syncthreads();
        }
        uint32_t c = part[t] - s;
        #pragma unroll
        for (int j = 0; j < 4; ++j){
            if (v[j] && rr >= c && rr < c + v[j]){ sb_sh = (uint32_t)(t*4 + j); r2_sh = rr - c; }
            c += v[j];
        }
    }
    __syncthreads();
    const uint32_t sb = sb_sh, r2 = r2_sh;
    __syncthreads();

    for (int i = t; i < 1024; i += 256) lh[i] = 0;
    __syncthreads();
    for (uint32_t i = t; i < n; i += 256){
        uint32_t k = f2k(cb[i]);
        if (((k >> 10) & 1023u) == sb) atomicAdd(&lh[k & 1023u], 1u);
    }
    __syncthreads();
    {
        uint32_t v[4]; uint32_t s = 0;
        #pragma unroll
        for (int j = 0; j < 4; ++j){ v[j] = lh[t*4 + j]; s += v[j]; }
        part[t] = s;
        __syncthreads();
        for (int d = 1; d < 256; d <<= 1){
            uint32_t add = (t >= d) ? part[t - d] : 0u;
            __syncthreads();
            part[t] += add;
            __syncthreads();
        }
        uint32_t c = part[t] - s;
        #pragma unroll
        for (int j = 0; j < 4; ++j){
            if (v[j] && r2 >= c && r2 < c + v[j]){
                uint32_t key = (b12 << 20) | (sb << 10) | (uint32_t)(t*4 + j);
                selval[r] = k2f(key);
            }
            c += v[j];
        }
    }
}

// ---- MAIN: 4-bin window, float2-packed (s1,s2) privatized LDS columns ----
__global__ void __launch_bounds__(128) k_main(const float* __restrict__ yt,
                                              const float* __restrict__ yp,
                                              const float* __restrict__ selval,
                                              double* __restrict__ acc){
    __shared__ float2 lpp[NBINS][128];  // 32 KB; lane t -> banks (2t,2t+1)%32: 2-way (free)
    __shared__ float qs[4];
    const int t = threadIdx.x;
    const int dir = blockIdx.y;
    #pragma unroll
    for (int k = 0; k < NBINS; ++k) lpp[k][t] = make_float2(0.f, 0.f);
    if (t == 0){
        double f01 = 0.01 * (double)(N_ELEM - 1) - 20971.0;     // 0.51
        double f99 = 0.99 * (double)(N_ELEM - 1) - 2076179.0;   // 0.49
        double v0 = selval[0], v1 = selval[1], v2 = selval[2], v3 = selval[3];
        double v4 = selval[4], v5 = selval[5], v6 = selval[6], v7 = selval[7];
        qs[0] = (float)(v0 + f01 * (v1 - v0));   // q01(y_true)
        qs[1] = (float)(v2 + f99 * (v3 - v2));   // q99(y_true)
        qs[2] = (float)(v4 + f01 * (v5 - v4));   // q01(y_pred)
        qs[3] = (float)(v6 + f99 * (v7 - v6));   // q99(y_pred)
    }
    __syncthreads();

    const float f_min = dir ? qs[0] : qs[2];
    const float f_max = dir ? qs[1] : qs[3];
    const float m_min = dir ? qs[2] : qs[0];
    const float m_max = dir ? qs[3] : qs[1];

    const float h      = (f_max - f_min) / 32.0f;
    const float vbc0   = f_min + 0.5f * h;
    const float vbcE   = f_max - 0.5f * h;
    const float step   = (vbcE - vbc0) / 31.0f;
    const float sigma  = step * (1.0f / 2.355f);
    const float preterm= 1.0f / (2.0f * sigma * sigma);
    const float negq2  = -preterm * step * step * 1.4426950408889634f;  // exp2 scale, u-units
    const float inv_st = 1.0f / step;
    const float u0     = -vbc0 * inv_st;

    const float4* ysrc = (const float4*)(dir ? yt : yp);   // target
    const float4* xsrc = (const float4*)(dir ? yp : yt);   // pred

    float sx = 0.f, sxx = 0.f;
    const int stride = gridDim.x * 128;
    for (int i = blockIdx.x * 128 + t; i < N_ELEM/4; i += stride){
        float4 y4 = ysrc[i];
        float4 x4 = xsrc[i];
        float yy[4] = {y4.x, y4.y, y4.z, y4.w};
        float xx[4] = {x4.x, x4.y, x4.z, x4.w};
        #pragma unroll
        for (int e = 0; e < 4; ++e){
            float yc = fminf(fmaxf(yy[e], f_min), f_max);
            float xc = fminf(fmaxf(xx[e], m_min), m_max);
            sx += xc; sxx = fmaf(xc, xc, sxx);
            float u  = fmaf(yc, inv_st, u0);                 // in [-0.5, 31.5]
            float jf = fminf(fmaxf(floorf(u) - 1.0f, 0.0f), 28.0f);
            int j0 = (int)jf;
            float t0 = u - jf;                               // window |u-k| <= 2; miss <= 1.6e-5 rel
            float2* p = &lpp[j0][t];
            #pragma unroll
            for (int w = 0; w < 4; ++w){
                float d  = t0 - (float)w;
                float wt = fexp2(d * d * negq2);
                float2 v = p[w*128];                         // ds_read_b64
                v.x += wt;
                v.y = fmaf(wt, xc, v.y);
                p[w*128] = v;                                // ds_write_b64
            }
        }
    }
    __syncthreads();

    // conflict-free column tree: 128 -> 32
    if (t < 64){
        #pragma unroll
        for (int k = 0; k < NBINS; ++k){
            float2 a0 = lpp[k][t], b0 = lpp[k][t+64];
            lpp[k][t] = make_float2(a0.x + b0.x, a0.y + b0.y);
        }
    }
    __syncthreads();
    if (t < 32){
        #pragma unroll
        for (int k = 0; k < NBINS; ++k){
            float2 a0 = lpp[k][t], b0 = lpp[k][t+32];
            lpp[k][t] = make_float2(a0.x + b0.x, a0.y + b0.y);
        }
    }
    __syncthreads();

    const int rep = blockIdx.x & (REPS - 1);
    double* a = acc + ((size_t)rep*2 + dir) * 66;
    if (t < 64){
        int arr = t >> 5, bin = t & 31;
        float s = 0.f;
        #pragma unroll
        for (int c = 0; c < 32; ++c){
            int cc = (c + t) & 31;   // staggered columns
            float2 v = lpp[bin][cc];
            s += arr ? v.y : v.x;
        }
        atomicAdd(&a[t], (double)s);
    }
    sx = wred(sx); sxx = wred(sxx);
    if ((t & 63) == 0){
        atomicAdd(&a[64], (double)sx);
        atomicAdd(&a[65], (double)sxx);
    }
}

// ---- FINAL: reduce replicas + scalar epilogue ----
__global__ void __launch_bounds__(256) k_final(const double* __restrict__ acc,
                                               float* __restrict__ out){
    __shared__ double dA[132];
    const int t = threadIdx.x;
    if (t < 132){
        int dir = t / 66, k = t % 66;
        double s = 0.0;
        #pragma unroll
        for (int rep = 0; rep < REPS; ++rep) s += acc[((size_t)rep*2 + dir)*66 + k];
        dA[t] = s;
    }
    __syncthreads();
    if (t == 0){
        const double eps = 1.1920928955078125e-07;  // finfo(float32).eps
        double res = 0.0;
        for (int dir = 0; dir < 2; ++dir){
            const double* A = &dA[dir*66];
            double sx = A[64], sxx = A[65];
            double tm = sx / (double)N_ELEM;
            double sumS1 = 0.0, bgv = 0.0;
            for (int k = 0; k < NBINS; ++k) sumS1 += A[k];
            for (int k = 0; k < NBINS; ++k){
                double mi = A[32+k] / (A[k] + eps);
                double d  = mi - tm;
                bgv += A[k] * d * d;
            }
            bgv /= (sumS1 + eps);
            double tv = (sxx - sx*sx/(double)N_ELEM) / (double)(N_ELEM - 1);
            res += bgv / (tv + eps);
        }
        out[0] = (float)(-0.5 * res);
    }
}

extern "C" void kernel_launch(void* const* d_in, const int* in_sizes, int n_in,
                              void* d_out, int out_size, void* d_ws, size_t ws_size,
                              hipStream_t stream){
    const float* yt = (const float*)d_in[0];
    const float* yp = (const float*)d_in[1];
    char* ws = (char*)d_ws;
    uint32_t* hist12   = (uint32_t*)(ws + OFF_H12);
    uint32_t* bucket12 = (uint32_t*)(ws + OFF_B12);
    uint32_t* resid12  = (uint32_t*)(ws + OFF_R12);
    uint32_t* cnt      = (uint32_t*)(ws + OFF_CNT);
    float*    selval   = (float*)(ws + OFF_SEL);
    double*   acc      = (double*)(ws + OFF_ACC);
    float*    cand     = (float*)(ws + OFF_CAND);

    k_zero<<<16, 256, 0, stream>>>((uint32_t*)ws);
    k_p1  <<<dim3(256, 2), 256, 0, stream>>>(yt, yp, hist12);
    k_s1  <<<2, 256, 0, stream>>>(hist12, bucket12, resid12);
    k_p2  <<<dim3(128, 2), 256, 0, stream>>>(yt, yp, bucket12, cnt, cand);
    k_s2  <<<8, 256, 0, stream>>>(cand, cnt, bucket12, resid12, selval);
    k_main<<<dim3(512, 2), 128, 0, stream>>>(yt, yp, selval, acc);
    k_final<<<1, 256, 0, stream>>>(acc, (float*)d_out);
}